// Round 5
// baseline (512.503 us; speedup 1.0000x reference)
//
#include <hip/hip_runtime.h>

#define BS   16
#define NMEM 256
#define NQ   63
#define T    64          // NQ + 1
#define D    512
#define H    512
#define G4   2048        // 4*H

#define K2C  2.885390081777927f   // 2*log2(e)

typedef __attribute__((ext_vector_type(8))) short short8;
typedef __attribute__((ext_vector_type(4))) float float4v;

// ---------------- workspace layout (float offsets) ----------------
enum : size_t {
    OFF_XW  = 0,                            // [T][BS][G4]
    OFF_YS  = OFF_XW  + (size_t)T*BS*G4,    // [T+1][BS][H]  (fp32, b-major, for q-gemm)
    OFF_HB  = OFF_YS  + (size_t)(T+1)*BS*H, // [T+1][8192] uint: bf16 hi | lo<<16
    OFF_AF  = OFF_HB  + (size_t)(T+1)*BS*H, // [BS][NMEM][H]
    OFF_Q   = OFF_AF  + (size_t)BS*NMEM*H,  // [T][BS][H]
    OFF_X   = OFF_Q   + (size_t)T*BS*H,     // [T][BS][D]
    OFF_B   = OFF_X   + (size_t)T*BS*D,     // [G4]
    OFF_BAR = OFF_B   + (size_t)G4,         // 1024 ints: 32 h-flags (stride 16) + 16 xW counters (stride 16)
};

__device__ inline unsigned short bf16_rn(float x) {
    union { float f; unsigned u; } a; a.f = x;
    unsigned r = a.u + 0x7FFFu + ((a.u >> 16) & 1u);
    return (unsigned short)(r >> 16);
}
__device__ inline float bf16_to_f(unsigned short s) {
    union { float f; unsigned u; } a; a.u = ((unsigned)s) << 16;
    return a.f;
}

// ---------------- prep: build x, bias, hbuf[0] ----------------
__global__ void prep(const float* __restrict__ lstm_in, const float* __restrict__ init_h,
                     const float* __restrict__ init_i,
                     const float* __restrict__ b_ih, const float* __restrict__ b_hh,
                     float* __restrict__ xbuf, float* __restrict__ biasbuf,
                     unsigned* __restrict__ hb0)
{
    int i = blockIdx.x * blockDim.x + threadIdx.x;
    const int NX = T*BS*D;
    if (i < NX) {
        int d = i & 511; int r = i >> 9; int t = r >> 4; int b = r & 15;
        float v = (t == 0) ? init_i[d] : lstm_in[((size_t)(b*NQ) + (t-1))*D + d];
        __builtin_nontemporal_store(v, xbuf + i);
    } else if (i < NX + G4) {
        int j = i - NX; biasbuf[j] = b_ih[j] + b_hh[j];
    } else if (i < NX + G4 + 8192) {
        int e = i - (NX + G4);
        int iw = e & 7;
        int k = ((e >> 3) >> 4) * 8 + iw;
        float h0 = init_h[k];
        unsigned hi = bf16_rn(h0);
        unsigned lo = bf16_rn(h0 - bf16_to_f((unsigned short)hi));
        hb0[e] = hi | (lo << 16);
    }
}

// ---------------- split-bf16 MFMA GEMM unit ----------------
// 256 threads compute a 64x64 C tile of A[M,K] @ op(B), fp32 in/out.
// BT=true: B is [N,K] (C = A*B^T). BT=false: B is [K,N].
// AT=true: write-through agent-scope atomic stores (no dirty L2).
template<bool BT, bool AT>
__device__ inline void gemm_unit(const float* __restrict__ A, const float* __restrict__ B,
                                 float* __restrict__ C, const float* __restrict__ bias,
                                 int N, int K, int tm, int tn, int t2)
{
    const int w = t2 >> 6, lane = t2 & 63;
    const int quad = lane >> 4, l15 = lane & 15;
    const int am = tm + w*16 + l15;
    float4v acch[4] = {{0,0,0,0},{0,0,0,0},{0,0,0,0},{0,0,0,0}};
    float4v accl[4] = {{0,0,0,0},{0,0,0,0},{0,0,0,0},{0,0,0,0}};
    for (int k0 = 0; k0 < K; k0 += 32) {
        const float* ap = A + (size_t)am*K + k0 + quad*8;
        float4 a0 = *(const float4*)ap, a1 = *(const float4*)(ap+4);
        float av[8] = {a0.x,a0.y,a0.z,a0.w,a1.x,a1.y,a1.z,a1.w};
        short8 ah, al;
#pragma unroll
        for (int i = 0; i < 8; ++i) {
            unsigned short hi = bf16_rn(av[i]);
            ah[i] = (short)hi; al[i] = (short)bf16_rn(av[i] - bf16_to_f(hi));
        }
#pragma unroll
        for (int ni = 0; ni < 4; ++ni) {
            const int n = tn + ni*16 + l15;
            float bv[8];
            if (BT) {
                const float* bp = B + (size_t)n*K + k0 + quad*8;
                float4 b0 = *(const float4*)bp, b1 = *(const float4*)(bp+4);
                bv[0]=b0.x; bv[1]=b0.y; bv[2]=b0.z; bv[3]=b0.w;
                bv[4]=b1.x; bv[5]=b1.y; bv[6]=b1.z; bv[7]=b1.w;
            } else {
                const float* bp = B + (size_t)(k0 + quad*8)*N + n;
#pragma unroll
                for (int i = 0; i < 8; ++i) bv[i] = bp[(size_t)i*N];
            }
            short8 bh, bl;
#pragma unroll
            for (int i = 0; i < 8; ++i) {
                unsigned short hi = bf16_rn(bv[i]);
                bh[i] = (short)hi; bl[i] = (short)bf16_rn(bv[i] - bf16_to_f(hi));
            }
            acch[ni] = __builtin_amdgcn_mfma_f32_16x16x32_bf16(ah, bh, acch[ni], 0, 0, 0);
            accl[ni] = __builtin_amdgcn_mfma_f32_16x16x32_bf16(al, bh, accl[ni], 0, 0, 0);
            accl[ni] = __builtin_amdgcn_mfma_f32_16x16x32_bf16(ah, bl, accl[ni], 0, 0, 0);
        }
    }
#pragma unroll
    for (int ni = 0; ni < 4; ++ni) {
        const int n = tn + ni*16 + l15;
        float bb = bias ? bias[n] : 0.f;
        float4v r = acch[ni] + accl[ni];
#pragma unroll
        for (int j = 0; j < 4; ++j) {
            int row = tm + w*16 + quad*4 + j;
            float val = r[j] + bb;
            if (AT)
                __hip_atomic_store(C + (size_t)row*N + n, val,
                                   __ATOMIC_RELAXED, __HIP_MEMORY_SCOPE_AGENT);
            else
                __builtin_nontemporal_store(val, C + (size_t)row*N + n);
        }
    }
}

template<bool BT>
__global__ __launch_bounds__(256) void gemm_mfma(const float* __restrict__ A,
                                                 const float* __restrict__ B,
                                                 float* __restrict__ C,
                                                 const float* __restrict__ bias,
                                                 int N, int K)
{
    gemm_unit<BT, false>(A, B, C, bias, N, K, blockIdx.y*64, blockIdx.x*64, threadIdx.x);
}

// ---------------- mega kernel ----------------
// blocks 0-31:   persistent LSTM recurrence (weights in VGPRs, split-bf16 MFMA)
// blocks 32-255: 448 units; first xW = x@w_ih^T+b tiles (release counters per
//                m-tile group), then af = ks@wm tiles. All outputs write-through.
// Zero cache-maintenance steady state: h exchanged via write-through atomics,
// read via relaxed atomic loads; the only release is the tiny h-flag store
// (wbl2 finds an empty dirty set).
__global__ __launch_bounds__(512, 2) void mega(
    float* __restrict__ xW,              // [T][BS][G4]
    const float* __restrict__ w_hh,      // [G4][H]
    const float* __restrict__ init_c,    // [H]
    const float* __restrict__ ks,        // [BS*NMEM][D]
    const float* __restrict__ wm,        // [D][H]
    const float* __restrict__ xb,        // [T*BS][D]
    const float* __restrict__ w_ih,      // [G4][D]
    const float* __restrict__ bias,      // [G4]
    float* __restrict__ ys,              // [T+1][BS][H]
    unsigned* __restrict__ hbuf,         // [T+1][8192]
    float* __restrict__ af,              // [BS*NMEM][H]
    int* __restrict__ flags)             // [0..511] h-flags, [512..767] xW counters
{
    const int tid = threadIdx.x;
    int* hflag = flags;
    int* xcnt  = flags + 512;

    if (blockIdx.x >= 32) {
        const int u  = (blockIdx.x - 32)*2 + (tid >> 8);
        const int t2 = tid & 255;
        // phase 1: xW tiles (M=1024 -> 16 m-tiles x 32 n-tiles)
        for (int tau = u; tau < 512; tau += 448) {
            const int mt = tau >> 5, ntt = tau & 31;
            gemm_unit<true, true>(xb, w_ih, xW, bias, G4, D, mt*64, ntt*64, t2);
            __syncthreads();   // both units of this block: all stores complete
            if (t2 == 0)
                __hip_atomic_fetch_add(&xcnt[mt*16], 1, __ATOMIC_RELEASE, __HIP_MEMORY_SCOPE_AGENT);
        }
        // phase 2: af tiles (M=4096 -> 64 m-tiles x 8 n-tiles)
        for (int tau = u; tau < 512; tau += 448) {
            const int mt = tau >> 3, ntt = tau & 7;
            gemm_unit<false, true>(ks, wm, af, nullptr, H, D, mt*64, ntt*64, t2);
        }
        return;
    }

    // ---------- LSTM recurrence ----------
    __shared__ float smem[3328];
    float* part = smem;              // [8][64][4]
    float* cst  = smem + 2048;       // [16][16]
    float* xwb  = smem + 2304;       // [4][16][16]  (gate, b, j16) staged xW[t]

    const int jt    = blockIdx.x;
    const int w     = tid >> 6;
    const int g     = w >> 1;
    const int khalf = w & 1;
    const int lane  = tid & 63;
    const int quad  = lane >> 4;
    const int l15   = lane & 15;

    // one-time weight preload -> bf16 hi/lo B-fragments in VGPRs
    short8 bh[8], bl[8];
    {
        const int row = g*512 + jt*16 + l15;
        const float* wr = w_hh + (size_t)row*H + khalf*256 + quad*8;
#pragma unroll
        for (int kt = 0; kt < 8; ++kt) {
            const float* wp = wr + kt*32;
#pragma unroll
            for (int i = 0; i < 8; ++i) {
                float v = wp[i];
                unsigned short hi = bf16_rn(v);
                bh[kt][i] = (short)hi;
                bl[kt][i] = (short)bf16_rn(v - bf16_to_f(hi));
            }
        }
    }

    const int b2 = tid >> 4, j16 = tid & 15;       // finalize mapping (tid<256)
    if (tid < 256) cst[b2*16 + j16] = init_c[jt*16 + j16];
    if (tid >= 256) {                              // wait for xW m-group 0, stage xW[0]
        while (__hip_atomic_load(&xcnt[0], __ATOMIC_RELAXED, __HIP_MEMORY_SCOPE_AGENT) < 32)
            __builtin_amdgcn_s_sleep(1);
        int ti = tid - 256;
        int bb = ti >> 4, s = ti & 15;
        int gg = s & 3, j4 = (s >> 2) << 2;
        float4 v = *(const float4*)(xW + (size_t)bb*G4 + gg*512 + jt*16 + j4);
        float* dst = xwb + gg*256 + bb*16 + j4;
        dst[0]=v.x; dst[1]=v.y; dst[2]=v.z; dst[3]=v.w;
    }
    __syncthreads();

    union U8 { unsigned u[4]; short8 s; };

    for (int t = 0; t < T; ++t) {
        // ---- load h_t A-fragments (relaxed agent atomics -> coherent point) ----
        const unsigned long long* hp = (const unsigned long long*)(hbuf + (size_t)t*8192);
        short8 ah[8], al[8];
#pragma unroll
        for (int kt = 0; kt < 8; ++kt) {
            const int base = ((((khalf*8 + kt)*4 + quad)*16 + l15) << 2);
            unsigned long long q0 = __hip_atomic_load(hp + base + 0, __ATOMIC_RELAXED, __HIP_MEMORY_SCOPE_AGENT);
            unsigned long long q1 = __hip_atomic_load(hp + base + 1, __ATOMIC_RELAXED, __HIP_MEMORY_SCOPE_AGENT);
            unsigned long long q2 = __hip_atomic_load(hp + base + 2, __ATOMIC_RELAXED, __HIP_MEMORY_SCOPE_AGENT);
            unsigned long long q3 = __hip_atomic_load(hp + base + 3, __ATOMIC_RELAXED, __HIP_MEMORY_SCOPE_AGENT);
            U8 Ah, Al;
            unsigned u0, u1;
            u0 = (unsigned)q0; u1 = (unsigned)(q0 >> 32);
            Ah.u[0] = (u0 & 0xffffu) | (u1 << 16);  Al.u[0] = (u0 >> 16) | (u1 & 0xffff0000u);
            u0 = (unsigned)q1; u1 = (unsigned)(q1 >> 32);
            Ah.u[1] = (u0 & 0xffffu) | (u1 << 16);  Al.u[1] = (u0 >> 16) | (u1 & 0xffff0000u);
            u0 = (unsigned)q2; u1 = (unsigned)(q2 >> 32);
            Ah.u[2] = (u0 & 0xffffu) | (u1 << 16);  Al.u[2] = (u0 >> 16) | (u1 & 0xffff0000u);
            u0 = (unsigned)q3; u1 = (unsigned)(q3 >> 32);
            Ah.u[3] = (u0 & 0xffffu) | (u1 << 16);  Al.u[3] = (u0 >> 16) | (u1 & 0xffff0000u);
            ah[kt] = Ah.s; al[kt] = Al.s;
        }
        // ---- split-bf16 MFMA ----
        float4v a0 = {0.f,0.f,0.f,0.f}, a1 = {0.f,0.f,0.f,0.f};
#pragma unroll
        for (int kt = 0; kt < 8; ++kt) {
            a0 = __builtin_amdgcn_mfma_f32_16x16x32_bf16(ah[kt], bh[kt], a0, 0, 0, 0);
            a1 = __builtin_amdgcn_mfma_f32_16x16x32_bf16(al[kt], bh[kt], a1, 0, 0, 0);
            a1 = __builtin_amdgcn_mfma_f32_16x16x32_bf16(ah[kt], bl[kt], a1, 0, 0, 0);
        }
        a0 += a1;
        *(float4v*)&part[(w*64 + lane)*4] = a0;    // D: m(b)=quad*4+reg, n(j)=lane&15
        __syncthreads();

        // ---- finalize: 256 threads = (b2, j16) ----
        if (tid < 256) {
            const int lsrc = ((b2 >> 2)*16 + j16)*4, r = b2 & 3;
            float gi = part[(0*256) + lsrc + r] + part[(1*256) + lsrc + r] + xwb[0*256 + b2*16 + j16];
            float gf = part[(2*256) + lsrc + r] + part[(3*256) + lsrc + r] + xwb[1*256 + b2*16 + j16];
            float gg = part[(4*256) + lsrc + r] + part[(5*256) + lsrc + r] + xwb[2*256 + b2*16 + j16];
            float go = part[(6*256) + lsrc + r] + part[(7*256) + lsrc + r] + xwb[3*256 + b2*16 + j16];
            float si = 1.f/(1.f+__expf(-gi));
            float sf = 1.f/(1.f+__expf(-gf));
            float so = 1.f/(1.f+__expf(-go));
            float cn = sf*cst[b2*16 + j16] + si*tanhf(gg);
            float hn = so*tanhf(cn);
            cst[b2*16 + j16] = cn;
            __hip_atomic_store(ys + (size_t)(t+1)*BS*H + b2*H + jt*16 + j16, hn,
                               __ATOMIC_RELAXED, __HIP_MEMORY_SCOPE_AGENT);
            const int k = jt*16 + j16;
            const int e = ((k >> 3)*16 + b2)*8 + (k & 7);
            unsigned hi = bf16_rn(hn);
            unsigned lo = bf16_rn(hn - bf16_to_f((unsigned short)hi));
            __hip_atomic_store(hbuf + (size_t)(t+1)*8192 + e, hi | (lo << 16),
                               __ATOMIC_RELAXED, __HIP_MEMORY_SCOPE_AGENT);
        }
        __syncthreads();   // vmcnt drain: all write-through stores complete

        if (t < T-1) {
            if (tid == 0)      // release orders h stores; L2 has no dirty lines -> cheap
                __hip_atomic_store(&hflag[jt*16], t+1, __ATOMIC_RELEASE, __HIP_MEMORY_SCOPE_AGENT);
            if (tid >= 256) {  // wait xW group, stage xW[t+1] under the flag wait
                const int grp = ((t+1) >> 2) * 16;
                while (__hip_atomic_load(&xcnt[grp], __ATOMIC_RELAXED, __HIP_MEMORY_SCOPE_AGENT) < 32)
                    __builtin_amdgcn_s_sleep(1);
                int ti = tid - 256;
                int bb = ti >> 4, s = ti & 15;
                int gg2 = s & 3, j4 = (s >> 2) << 2;
                float4 v = *(const float4*)(xW + (size_t)(t+1)*BS*G4 + bb*G4 + gg2*512 + jt*16 + j4);
                float* dst = xwb + gg2*256 + bb*16 + j4;
                dst[0]=v.x; dst[1]=v.y; dst[2]=v.z; dst[3]=v.w;
            }
            if (tid < 64) {    // wave-parallel poll of 32 flags (1 memory op/iter)
                const int fidx = (tid & 31) << 4;
                for (;;) {
                    int v = __hip_atomic_load(&hflag[fidx], __ATOMIC_RELAXED, __HIP_MEMORY_SCOPE_AGENT);
                    if (__all(v >= t+1)) break;
                    __builtin_amdgcn_s_sleep(1);
                }
            }
            __syncthreads();
        }
    }
}

// ---------------- fused attention: score[b,t,m] = sum_h tanh(af+q)*v ----------------
__global__ __launch_bounds__(256) void attn(const float* __restrict__ af,
                                            const float* __restrict__ q,
                                            const float* __restrict__ v,
                                            float* __restrict__ out)
{
    __shared__ float afs[64][68];
    __shared__ float qs[4][516];
    __shared__ float vs[512];
    const int tid = threadIdx.x;
    const int mc = blockIdx.x, tc = blockIdx.y, b = blockIdx.z;
    for (int i = tid; i < 4*128; i += 256) {
        int t = i >> 7, h4 = (i & 127) << 2;
        float4 x = *(const float4*)(q + ((size_t)((tc*4 + t)*16 + b) << 9) + h4);
        x.x *= K2C; x.y *= K2C; x.z *= K2C; x.w *= K2C;
        *(float4*)&qs[t][h4] = x;
    }
    for (int i = tid; i < 128; i += 256)
        *(float4*)&vs[i << 2] = *(const float4*)(v + (i << 2));
    const int ml = tid & 63, tg = tid >> 6;
    float acc = 0.f;
    for (int hc = 0; hc < 8; ++hc) {
        __syncthreads();
        for (int i = tid; i < 64*16; i += 256) {
            int m = i >> 4, h4 = (i & 15) << 2;
            float4 x = *(const float4*)(af + ((size_t)(b*NMEM + mc*64 + m) << 9) + hc*64 + h4);
            x.x *= K2C; x.y *= K2C; x.z *= K2C; x.w *= K2C;
            *(float4*)&afs[m][h4] = x;
        }
        __syncthreads();
#pragma unroll
        for (int h8 = 0; h8 < 8; ++h8) {
            float4 a0 = *(const float4*)&afs[ml][h8*8 + 0];
            float4 a1 = *(const float4*)&afs[ml][h8*8 + 4];
            float4 v0 = *(const float4*)&vs[hc*64 + h8*8 + 0];
            float4 v1 = *(const float4*)&vs[hc*64 + h8*8 + 4];
            float4 q0 = *(const float4*)&qs[tg][hc*64 + h8*8 + 0];
            float4 q1 = *(const float4*)&qs[tg][hc*64 + h8*8 + 4];
            const float* ap0 = (const float*)&a0; const float* ap1 = (const float*)&a1;
            const float* vp0 = (const float*)&v0; const float* vp1 = (const float*)&v1;
            const float* qp0 = (const float*)&q0; const float* qp1 = (const float*)&q1;
            float s = acc;
#pragma unroll
            for (int j = 0; j < 4; ++j) {
                float e = exp2f(ap0[j] + qp0[j]);
                s = fmaf(vp0[j], __builtin_amdgcn_rcpf(e + 1.f), s);
            }
#pragma unroll
            for (int j = 0; j < 4; ++j) {
                float e = exp2f(ap1[j] + qp1[j]);
                s = fmaf(vp1[j], __builtin_amdgcn_rcpf(e + 1.f), s);
            }
            acc = s;
        }
    }
    float Sv = 0.f;
    for (int i = 0; i < 512; i += 4) {
        float4 t4 = *(const float4*)&vs[i];
        Sv += t4.x + t4.y + t4.z + t4.w;
    }
    out[((size_t)b*T + tc*4 + tg)*NMEM + mc*64 + ml] = Sv - 2.f*acc;
}

extern "C" void kernel_launch(void* const* d_in, const int* in_sizes, int n_in,
                              void* d_out, int out_size, void* d_ws, size_t ws_size,
                              hipStream_t stream)
{
    const float* ks      = (const float*)d_in[0];
    const float* lstm_in = (const float*)d_in[2];
    const float* init_h  = (const float*)d_in[3];
    const float* init_c  = (const float*)d_in[4];
    const float* init_i  = (const float*)d_in[5];
    const float* w_ih    = (const float*)d_in[6];
    const float* w_hh    = (const float*)d_in[7];
    const float* b_ih    = (const float*)d_in[8];
    const float* b_hh    = (const float*)d_in[9];
    const float* wm      = (const float*)d_in[10];
    const float* wq      = (const float*)d_in[11];
    const float* av      = (const float*)d_in[12];

    float* ws   = (float*)d_ws;
    float* xW   = ws + OFF_XW;
    float* ys   = ws + OFF_YS;
    unsigned* hbuf = (unsigned*)(ws + OFF_HB);
    float* af   = ws + OFF_AF;
    float* qb   = ws + OFF_Q;
    float* xb   = ws + OFF_X;
    float* bias = ws + OFF_B;
    int*   flags= (int*)(ws + OFF_BAR);

    hipMemsetAsync(flags, 0, 1024*sizeof(int), stream);

    const int prep_n = T*BS*D + G4 + 8192;
    prep<<<(prep_n + 255)/256, 256, 0, stream>>>(lstm_in, init_h, init_i,
                                                 b_ih, b_hh, xb, bias, hbuf);
    // xW tiles + LSTM recurrence + af tiles, one persistent kernel
    mega<<<256, 512, 0, stream>>>(xW, w_hh, init_c, ks, wm, xb, w_ih, bias,
                                  ys, hbuf, af, flags);
    // qb[1024,512] = ys[1..64] @ wq       (split-bf16 MFMA)
    gemm_mfma<false><<<dim3(8, 16), 256, 0, stream>>>(ys + BS*H, wq, qb, nullptr, H, H);
    attn<<<dim3(4, 16, 16), 256, 0, stream>>>(af, qb, av, (float*)d_out);
}